// Round 1
// 143.151 us; speedup vs baseline: 1.0452x; 1.0452x over previous
//
#include <hip/hip_runtime.h>
#include <hip/hip_bf16.h>

#define N_NODES 100000
#define N_EDGES 1600000
#define HID 64

#define NG 196          // nodes per group
#define GROUPS 511      // ceil(100000/196)
#define GSTRIDE 512     // padded stride for counters/regions
#define NREP 2          // replica regions per group
#define RCAP 2048       // pairs per (replica,group); mean ~1564, +12 sigma
#define EPT 16          // edges per thread in bin path (256 thr -> 4096/block)
#define BIN_BLOCKS 391  // ceil(1600000/4096)
#define LIN_BLOCKS 1563 // ceil(6250 tiles / 4 waves per block)

// gather kernel geometry
#define TILES 13        // ceil(196/16) 16-node MFMA tiles per group
#define TCAP 384        // slots per tile list; Poisson(256), +8 sigma
#define GTHREADS 768
#define GWAVES 12

using bf16 = __hip_bfloat16;
typedef __attribute__((ext_vector_type(8))) short short8;
typedef __attribute__((ext_vector_type(4))) short short4v;
typedef __attribute__((ext_vector_type(4))) float float4v;

__device__ __forceinline__ float bfbits2f(unsigned short u) {
    union { unsigned int i; float f; } v;
    v.i = ((unsigned int)u) << 16;
    return v.f;
}
__device__ __forceinline__ unsigned short f2bfbits(float f) {
    union { float f; unsigned int i; } v;
    v.f = f;
    unsigned int r = v.i + 0x7fffu + ((v.i >> 16) & 1u);  // RNE; finite inputs
    return (unsigned short)(r >> 16);
}

// Init: zero ALL group cursors; build W fragment-order planes so prep2's
// B-frag loads are lane-contiguous: Wf[((nt*2+ks)*64 + l)*8 + j] holds
// W[nt*16+(l&15)][ks*32+(l>>4)*8+j] split into bf16 hi/lo.
__global__ __launch_bounds__(256) void k_init(
    const float* __restrict__ W, int* __restrict__ gcur,
    unsigned short* __restrict__ Wfhi, unsigned short* __restrict__ Wflo)
{
    const int t = blockIdx.x * 256 + threadIdx.x;
    for (int i = t; i < NREP * GSTRIDE; i += 512) gcur[i] = 0;
    for (int o = t; o < HID * HID; o += 512) {
        const int j = o & 7, l = (o >> 3) & 63, ksnt = o >> 9;
        const int ks = ksnt & 1, nt = ksnt >> 1;
        const int c = l & 15, q = l >> 4;
        const float f = W[(size_t)(nt * 16 + c) * HID + ks * 32 + q * 8 + j];
        const unsigned short h = f2bfbits(f);
        Wfhi[o] = h;
        Wflo[o] = f2bfbits(f - bfbits2f(h));
    }
}

// Fused: blocks [0,LIN_BLOCKS) = MFMA linear (4 waves x one 16-node tile each;
// x staged via LDS so global reads are coalesced; W-frags from pre-swizzled
// planes so B loads are lane-contiguous). Blocks [LIN_BLOCKS,...) = binning.
__global__ __launch_bounds__(256, 4) void k_prep2(
    const float* __restrict__ x, const unsigned short* __restrict__ Wfhi,
    const unsigned short* __restrict__ Wflo, const float* __restrict__ b,
    bf16* __restrict__ m,
    const int* __restrict__ edges, int* __restrict__ gcur,
    int* __restrict__ binned)
{
    __shared__ union SM {
        struct { float xs[64 * 65]; } lin;                    // 16.6 KB, pad 65
        struct { int cnt[GSTRIDE]; int base[GSTRIDE]; } bin;  // 4 KB
    } sm;
    const int t = threadIdx.x;

    if (blockIdx.x < LIN_BLOCKS) {
        // Stage 64 node rows coalesced into LDS (padded stride 65).
        const int nb0 = blockIdx.x * 64;
        const float4* xg = reinterpret_cast<const float4*>(x) + (size_t)nb0 * 16;
        #pragma unroll
        for (int k = 0; k < 4; ++k) {
            const int f4 = t + k * 256;                 // float4 idx within block
            float4 v = make_float4(0.f, 0.f, 0.f, 0.f);
            if (nb0 * 16 + f4 < N_NODES * 16) v = xg[f4];
            const int r = f4 >> 4, fc = (f4 & 15) * 4;
            float* dst = &sm.lin.xs[r * 65 + fc];
            dst[0] = v.x; dst[1] = v.y; dst[2] = v.z; dst[3] = v.w;
        }
        __syncthreads();

        const int wv = t >> 6, l = t & 63;
        const int c = l & 15, q = l >> 4;
        const int tile = blockIdx.x * 4 + wv;
        if (tile >= N_NODES / 16) return;   // 6250 tiles cover 100k nodes exactly
        const int nb = tile * 16;

        // B-frags: lane-contiguous loads from pre-swizzled planes.
        const short8* wfh = reinterpret_cast<const short8*>(Wfhi);
        const short8* wfl = reinterpret_cast<const short8*>(Wflo);
        short8 Bhi[4][2], Blo[4][2];
        #pragma unroll
        for (int nt = 0; nt < 4; ++nt)
            #pragma unroll
            for (int ks = 0; ks < 2; ++ks) {
                const int fi = (nt * 2 + ks) * 64 + l;
                Bhi[nt][ks] = wfh[fi];
                Blo[nt][ks] = wfl[fi];
            }

        // A-frags from LDS (bank-conflict-free via pad), bf16 RNE convert.
        short8 Ahi[2];
        #pragma unroll
        for (int ks = 0; ks < 2; ++ks) {
            const float* xsrc = &sm.lin.xs[(wv * 16 + c) * 65 + ks * 32 + q * 8];
            #pragma unroll
            for (int j = 0; j < 8; ++j)
                Ahi[ks][j] = (short)f2bfbits(xsrc[j]);
        }

        float4v acc[4];
        #pragma unroll
        for (int nt = 0; nt < 4; ++nt) {
            const float bias = b[nt * 16 + c];
            acc[nt] = (float4v){bias, bias, bias, bias};
            #pragma unroll
            for (int ks = 0; ks < 2; ++ks) {
                acc[nt] = __builtin_amdgcn_mfma_f32_16x16x32_bf16(Ahi[ks], Bhi[nt][ks], acc[nt], 0, 0, 0);
                acc[nt] = __builtin_amdgcn_mfma_f32_16x16x32_bf16(Ahi[ks], Blo[nt][ks], acc[nt], 0, 0, 0);
            }
        }

        // C/D: col c = feature nt*16+c, row q*4+rg = node nb+q*4+rg
        unsigned short* mp = reinterpret_cast<unsigned short*>(m);
        #pragma unroll
        for (int nt = 0; nt < 4; ++nt)
            #pragma unroll
            for (int rg = 0; rg < 4; ++rg) {
                const float v = fmaxf(acc[nt][rg], 0.0f);
                mp[(size_t)(nb + q * 4 + rg) * HID + nt * 16 + c] = f2bfbits(v);
            }
    } else {
        int* cnt  = sm.bin.cnt;
        int* base = sm.bin.base;
        const int bb = blockIdx.x - LIN_BLOCKS;
        for (int i = t; i < GSTRIDE; i += 256) cnt[i] = 0;
        __syncthreads();

        const int e0 = bb * (256 * EPT);
        int gk[EPT], pk[EPT], sl[EPT];
        #pragma unroll
        for (int k = 0; k < EPT; ++k) {
            const int e = e0 + k * 256 + t;   // coalesced per k
            if (e < N_EDGES) {
                const int dst = edges[e];             // target
                const int src = edges[N_EDGES + e];   // source
                const int g = (int)((unsigned)dst / NG);   // magic-mul div
                gk[k] = g;
                pk[k] = ((dst - g * NG) << 17) | src;  // dl(8b) | src(17b)
                sl[k] = atomicAdd(&cnt[g], 1);
            } else gk[k] = -1;
        }
        __syncthreads();
        const int r = bb & (NREP - 1);
        for (int i = t; i < GROUPS; i += 256) {
            const int cc = cnt[i];
            base[i] = cc ? atomicAdd(&gcur[r * GSTRIDE + i], cc) : 0;
        }
        __syncthreads();
        #pragma unroll
        for (int k = 0; k < EPT; ++k) {
            if (gk[k] >= 0) {
                const int pos = base[gk[k]] + sl[k];
                if ((unsigned)pos < RCAP)   // unsigned: rejects corruption too
                    binned[(size_t)(r * GSTRIDE + gk[k]) * RCAP + pos] = pk[k];
            }
        }
    }
}

// hardware transpose read: per-lane addr = base + l*8; group q (l>>4) reads the
// 128B window at q*128: [4 slots][16 feats] bf16 row-major; lane gets feat l&15
// across the 4 slot-rows (learn_hip m156/m162 semantics).
#define TRREAD(dst, OFF) \
    asm volatile("ds_read_b64_tr_b16 %0, %1 offset:" #OFF \
                 : "=v"(dst) : "v"(traddr) : "memory")

// MFMA gather: one block (768 thr = 12 waves) per 196-node group. Per-tile
// (16 nodes) combined src lists in LDS; each wave owns tiles wv, wv+12.
// Per 32-slot chunk: stage 32 m-rows (bf16) into a private 2KB LDS buffer in
// two 16-row passes, ds_read_b64_tr_b16 the feat-major A-frags, and accumulate
// with mfma_f32_16x16x32_bf16 against a one-hot B (slot->node). D layout:
// col=l&15=node, row=q*4+reg=feat -> each lane ends with 16 contiguous feats of
// one node; fused residual + RMSNorm epilogue per tile (16x amortized).
__global__ __launch_bounds__(GTHREADS, 6) void k_gather_mfma(
    const float* __restrict__ x, const bf16* __restrict__ m,
    const int* __restrict__ gcur, const int* __restrict__ binned,
    const float* __restrict__ nw, const float* __restrict__ nbias,
    float* __restrict__ out)
{
    __shared__ int tcnt[TILES];
    __shared__ int tlist[TILES * TCAP];                 // 19968 B
    __shared__ uint4 stg4[GWAVES * 128];                // 24576 B: 2KB per wave

    const int t = threadIdx.x;
    const int g = blockIdx.x;
    if (t < TILES) tcnt[t] = 0;
    __syncthreads();

    // Build per-tile combined lists. pr = dl(8b)<<17 | src(17b);
    // tile = dl>>4 = pr>>21; tag keeps (dl&15)<<17 | src = pr & 0x1FFFFF.
    #pragma unroll
    for (int rr = 0; rr < NREP; ++rr) {
        int c = gcur[rr * GSTRIDE + g];
        if (c > RCAP) c = RCAP;
        const int* reg = binned + (size_t)(rr * GSTRIDE + g) * RCAP;
        for (int i = t; i < c; i += GTHREADS) {
            const int pr = reg[i];
            const int tile = pr >> 21;
            const int slot = atomicAdd(&tcnt[tile], 1);
            if (slot < TCAP) tlist[tile * TCAP + slot] = pr & 0x1FFFFF;
        }
    }
    __syncthreads();

    const int wv = t >> 6, l = t & 63;
    const int q = l >> 4;          // 16-lane group
    const int node16 = l & 15;     // node column this lane owns in D
    const int fq = l & 7;          // 16B segment within a 128B m-row (staging)
    const int sr = l >> 3;         // buffer row (0..7) staged per round
    // staging LDS byte offset inside the wave's 2KB buffer:
    // ftile*512 + subtile*128 + row*32 + half*16 ; +256 for round 1.
    const int stg_c = ((fq >> 1) << 9) | ((l >> 5) << 7) | ((sr & 3) << 5) | ((l & 1) << 4);
    // buffer row s holds logical chunk slot (s>>2)*8 + (s&3) (+4 in pass B)
    const int kq0 = ((sr >> 2) << 3) + (sr & 3);         // row sr      (round 0)
    const int kq1 = (((sr + 8) >> 2) << 3) + (sr & 3);   // row sr + 8  (round 1)
    char* stg_wave = (char*)(&stg4[0]) + (wv << 11);
    const unsigned traddr = (unsigned)(size_t)stg_wave + (unsigned)(l << 3);
    const uint4* mv = reinterpret_cast<const uint4*>(m);

    for (int tile = wv; tile < TILES; tile += GWAVES) {
        int K = tcnt[tile];
        if (K > TCAP) K = TCAP;
        const int lbase = tile * TCAP;
        float4v acc0 = {0.f, 0.f, 0.f, 0.f};
        float4v acc1 = acc0, acc2 = acc0, acc3 = acc0;
        const int nch = (K + 31) >> 5;

        for (int ch = 0; ch < nch; ++ch) {
            const int k0 = ch << 5;
            // --- issue all 4 row loads up front (pad slots -> row 0, masked by B) ---
            const int kA0 = k0 + kq0, kA1 = k0 + kq1;
            const int tA0i = (kA0 < K) ? tlist[lbase + kA0] : 0;
            const int tA1i = (kA1 < K) ? tlist[lbase + kA1] : 0;
            const int tB0i = (kA0 + 4 < K) ? tlist[lbase + kA0 + 4] : 0;
            const int tB1i = (kA1 + 4 < K) ? tlist[lbase + kA1 + 4] : 0;
            const uint4 vA0 = mv[(size_t)(tA0i & 0x1FFFF) * 8 + fq];
            const uint4 vA1 = mv[(size_t)(tA1i & 0x1FFFF) * 8 + fq];
            const uint4 vB0 = mv[(size_t)(tB0i & 0x1FFFF) * 8 + fq];
            const uint4 vB1 = mv[(size_t)(tB1i & 0x1FFFF) * 8 + fq];

            // --- pass A: slots {8i..8i+3}: store 16 rows, transpose-read frags ---
            *reinterpret_cast<uint4*>(stg_wave + stg_c) = vA0;
            *reinterpret_cast<uint4*>(stg_wave + stg_c + 256) = vA1;
            short4v tA0, tA1, tA2, tA3;
            TRREAD(tA0, 0); TRREAD(tA1, 512); TRREAD(tA2, 1024); TRREAD(tA3, 1536);

            // --- pass B: slots {8i+4..8i+7}: same buffer (DS pipe is in-order) ---
            *reinterpret_cast<uint4*>(stg_wave + stg_c) = vB0;
            *reinterpret_cast<uint4*>(stg_wave + stg_c + 256) = vB1;
            short4v tB0, tB1, tB2, tB3;
            TRREAD(tB0, 0); TRREAD(tB1, 512); TRREAD(tB2, 1024); TRREAD(tB3, 1536);

            // --- one-hot B operand: B[k][node] = 1.0bf16 iff seg(k) == node ---
            const int kb = k0 + (q << 3);
            short8 bh;
            #pragma unroll
            for (int jj = 0; jj < 8; ++jj) {
                const int kk = kb + jj;
                const int tb = (kk < K) ? tlist[lbase + kk] : -1;
                bh[jj] = (short)(((tb >> 17) == node16) ? 0x3F80 : 0);
            }

            asm volatile("s_waitcnt lgkmcnt(0)" ::: "memory");
            __builtin_amdgcn_sched_barrier(0);
            const short8 a0 = __builtin_shufflevector(tA0, tB0, 0, 1, 2, 3, 4, 5, 6, 7);
            const short8 a1 = __builtin_shufflevector(tA1, tB1, 0, 1, 2, 3, 4, 5, 6, 7);
            const short8 a2 = __builtin_shufflevector(tA2, tB2, 0, 1, 2, 3, 4, 5, 6, 7);
            const short8 a3 = __builtin_shufflevector(tA3, tB3, 0, 1, 2, 3, 4, 5, 6, 7);
            acc0 = __builtin_amdgcn_mfma_f32_16x16x32_bf16(a0, bh, acc0, 0, 0, 0);
            acc1 = __builtin_amdgcn_mfma_f32_16x16x32_bf16(a1, bh, acc1, 0, 0, 0);
            acc2 = __builtin_amdgcn_mfma_f32_16x16x32_bf16(a2, bh, acc2, 0, 0, 0);
            acc3 = __builtin_amdgcn_mfma_f32_16x16x32_bf16(a3, bh, acc3, 0, 0, 0);
        }

        // --- epilogue: residual + RMSNorm. Lane holds feats ft*16+q*4+{0..3} of
        // node g*NG + tile*16 + node16. ss partners (l^16,l^32,l^48) share node. ---
        const int dl = (tile << 4) + node16;
        const int n = g * NG + dl;
        if (dl < NG && n < N_NODES) {
            const float4* xr = reinterpret_cast<const float4*>(x) + (size_t)n * 16 + q;
            const float4 x0 = xr[0], x1 = xr[4], x2 = xr[8], x3 = xr[12];
            const float h00 = x0.x + acc0[0], h01 = x0.y + acc0[1], h02 = x0.z + acc0[2], h03 = x0.w + acc0[3];
            const float h10 = x1.x + acc1[0], h11 = x1.y + acc1[1], h12 = x1.z + acc1[2], h13 = x1.w + acc1[3];
            const float h20 = x2.x + acc2[0], h21 = x2.y + acc2[1], h22 = x2.z + acc2[2], h23 = x2.w + acc2[3];
            const float h30 = x3.x + acc3[0], h31 = x3.y + acc3[1], h32 = x3.z + acc3[2], h33 = x3.w + acc3[3];
            float ss = h00 * h00 + h01 * h01 + h02 * h02 + h03 * h03
                     + h10 * h10 + h11 * h11 + h12 * h12 + h13 * h13
                     + h20 * h20 + h21 * h21 + h22 * h22 + h23 * h23
                     + h30 * h30 + h31 * h31 + h32 * h32 + h33 * h33;
            ss += __shfl_xor(ss, 16, 64);
            ss += __shfl_xor(ss, 32, 64);
            const float inv = rsqrtf(ss * (1.0f / HID) + 1e-5f);
            const float4* nwp = reinterpret_cast<const float4*>(nw);
            const float4* nbp = reinterpret_cast<const float4*>(nbias);
            float4* op = reinterpret_cast<float4*>(out) + (size_t)n * 16 + q;
            {
                const float4 w = nwp[q], bb = nbp[q];
                float4 o;
                o.x = w.x * h00 * inv + bb.x; o.y = w.y * h01 * inv + bb.y;
                o.z = w.z * h02 * inv + bb.z; o.w = w.w * h03 * inv + bb.w;
                op[0] = o;
            }
            {
                const float4 w = nwp[4 + q], bb = nbp[4 + q];
                float4 o;
                o.x = w.x * h10 * inv + bb.x; o.y = w.y * h11 * inv + bb.y;
                o.z = w.z * h12 * inv + bb.z; o.w = w.w * h13 * inv + bb.w;
                op[4] = o;
            }
            {
                const float4 w = nwp[8 + q], bb = nbp[8 + q];
                float4 o;
                o.x = w.x * h20 * inv + bb.x; o.y = w.y * h21 * inv + bb.y;
                o.z = w.z * h22 * inv + bb.z; o.w = w.w * h23 * inv + bb.w;
                op[8] = o;
            }
            {
                const float4 w = nwp[12 + q], bb = nbp[12 + q];
                float4 o;
                o.x = w.x * h30 * inv + bb.x; o.y = w.y * h31 * inv + bb.y;
                o.z = w.z * h32 * inv + bb.z; o.w = w.w * h33 * inv + bb.w;
                op[12] = o;
            }
        }
    }
}

extern "C" void kernel_launch(void* const* d_in, const int* in_sizes, int n_in,
                              void* d_out, int out_size, void* d_ws, size_t ws_size,
                              hipStream_t stream) {
    const float* x     = (const float*)d_in[0];
    const int*   edges = (const int*)d_in[1];
    const float* W     = (const float*)d_in[2];
    const float* b     = (const float*)d_in[3];
    const float* nw    = (const float*)d_in[4];
    const float* nb    = (const float*)d_in[5];
    float* out = (float*)d_out;

    // Workspace: gcur 4KB | Wfhi 8KB @16K | Wflo 8KB @24K | binned 8MB @64K | m 12.8MB
    int* gcur = (int*)d_ws;
    unsigned short* Wfhi = (unsigned short*)((char*)d_ws + (1 << 14));
    unsigned short* Wflo = Wfhi + HID * HID;
    int*  binned = (int*)((char*)d_ws + (1 << 16));
    bf16* m      = (bf16*)((char*)d_ws + (1 << 16) +
                           (size_t)NREP * GSTRIDE * RCAP * sizeof(int));

    k_init<<<2, 256, 0, stream>>>(W, gcur, Wfhi, Wflo);
    k_prep2<<<LIN_BLOCKS + BIN_BLOCKS, 256, 0, stream>>>(x, Wfhi, Wflo, b, m, edges, gcur, binned);
    k_gather_mfma<<<GROUPS, GTHREADS, 0, stream>>>(x, m, gcur, binned, nw, nb, out);
}